// Round 8
// baseline (638.580 us; speedup 1.0000x reference)
//
#include <hip/hip_runtime.h>
#include <hip/hip_bf16.h>
#include <stdint.h>

// HadLinear: out = blockFWHT1024(x)/32 @ W^T  ==  x @ (blockFWHT1024(W rows)/32)^T
// (1) x f32->bf16, (2) Wh = FWHT(W)/32 -> bf16, (3) bf16 MFMA GEMM.
// GEMM R8 = R7 skeleton (single barrier/phase, VMC(4) post-MFMA @ph4/ph8,
// group-staged A, 8tm x 4tn XCD set) + boundary-respecting READ-AHEAD:
//  ph1/ph5: read all 12 frags (MFMA waits first 8 via compiler counted lgkm)
//  ph2/ph6: read k1's 8 under MFMA | ph3/ph7: read last 4 under MFMA
//  ph4/ph8: zero reads (pure MFMA) -> LDS drain overlaps MFMA in 6/8 phases.

typedef __attribute__((ext_vector_type(8))) short    short8;
typedef __attribute__((ext_vector_type(4))) float    f32x4;
typedef __attribute__((ext_vector_type(8))) uint16_t u16x8;

static constexpr int MDIM = 16384;
static constexpr int NDIM = 4096;
static constexpr int KDIM = 4096;
static constexpr int BM = 256, BN = 256, BK = 64;
static constexpr int NT = KDIM / BK;   // 64 K-tiles, 32 iterations

__device__ __forceinline__ uint16_t f2bf(float f) {
  union { float f; uint32_t u; } c; c.f = f;
  uint32_t u = c.u;
  return (uint16_t)((u + 0x7FFFu + ((u >> 16) & 1u)) >> 16);
}

__global__ __launch_bounds__(256) void cvt_x_kernel(const float* __restrict__ x,
                                                    uint16_t* __restrict__ xb, int n8) {
  int stride = gridDim.x * blockDim.x;
  for (int t = blockIdx.x * blockDim.x + threadIdx.x; t < n8; t += stride) {
    const float4* p = reinterpret_cast<const float4*>(x + (size_t)t * 8);
    float4 a = p[0], b = p[1];
    u16x8 o;
    o[0] = f2bf(a.x); o[1] = f2bf(a.y); o[2] = f2bf(a.z); o[3] = f2bf(a.w);
    o[4] = f2bf(b.x); o[5] = f2bf(b.y); o[6] = f2bf(b.z); o[7] = f2bf(b.w);
    *reinterpret_cast<u16x8*>(xb + (size_t)t * 8) = o;
  }
}

__global__ __launch_bounds__(256) void fwht_w_kernel(const float* __restrict__ W,
                                                     uint16_t* __restrict__ Wh) {
  __shared__ float s[1024];
  const int tid = threadIdx.x;
  const size_t base = (size_t)blockIdx.x * 1024;
  reinterpret_cast<float4*>(s)[tid] = reinterpret_cast<const float4*>(W + base)[tid];
  __syncthreads();
  for (int h = 1; h < 1024; h <<= 1) {
    #pragma unroll
    for (int pp = 0; pp < 2; ++pp) {
      int p = tid + pp * 256;
      int q = p & (h - 1);
      int i = ((p - q) << 1) | q;
      float a = s[i], b = s[i + h];
      s[i] = a + b;
      s[i + h] = a - b;
    }
    __syncthreads();
  }
  #pragma unroll
  for (int pp = 0; pp < 4; ++pp) {
    int i = tid + pp * 256;
    Wh[base + i] = f2bf(s[i] * 0.03125f);
  }
}

// ---------------- 8-phase GEMM: C[M,N] = A[M,K] * B[N,K]^T ----------------
// LDS tile: 256 rows x 8 chunks(16B), chunk (r,c') holds global c = c'^((r>>1)&7).

#define FENCE asm volatile("" ::: "memory")
#define SBAR  do { FENCE; __builtin_amdgcn_s_barrier(); \
                   __builtin_amdgcn_sched_barrier(0); } while (0)
#define SCHED0 __builtin_amdgcn_sched_barrier(0)
#define VMC(n) do { asm volatile("s_waitcnt vmcnt(" #n ")" ::: "memory"); \
                    __builtin_amdgcn_sched_barrier(0); } while (0)

#define LDA4(DST, BUF, MLO, KOFF)                                              \
  do { _Pragma("unroll")                                                       \
    for (int m_ = 0; m_ < 4; ++m_)                                             \
      DST[m_] = *(const short8*)(aRd + (BUF)*32768 + ((MLO)+m_)*2048 + (KOFF)); \
  } while (0)

#define LDB4(DST, BUF, KOFF)                                                   \
  do { _Pragma("unroll")                                                       \
    for (int n_ = 0; n_ < 4; ++n_)                                             \
      DST[n_] = *(const short8*)(bRd + (BUF)*32768 + n_*2048 + (KOFF));        \
  } while (0)

#define MF16(AF, BF, MB)                                                       \
  do { __builtin_amdgcn_s_setprio(1);                                          \
    _Pragma("unroll")                                                          \
    for (int m_ = 0; m_ < 4; ++m_)                                             \
      _Pragma("unroll")                                                        \
      for (int n_ = 0; n_ < 4; ++n_)                                           \
        acc[(MB)+m_][n_] = __builtin_amdgcn_mfma_f32_16x16x32_bf16(            \
            AF[m_], BF[n_], acc[(MB)+m_][n_], 0, 0, 0);                        \
    __builtin_amdgcn_s_setprio(0);                                             \
  } while (0)

// Reads (frags for phase p+1 issued at p where same-buffer):
//  ph1: bKa,aL,aH k0 (12) | ph2: bKb,aL k1 (8) | ph3: aH k1 (4) | ph4: none
//  ph5-8: same on buf1.  MFMA(p) waits only its own frags (compiler counted
//  lgkm: ph1 lgkm(4), ph2 lgkm(8), ph3 lgkm(4), ph4 lgkm(0)).
// Stages (R7 plan): ph1 T1.A.g1 | ph2 T1.B.h1 | ph4 T2.B.h0+A.g0 |
//  ph5 T2.A.g1 | ph6 T2.B.h1 | ph8 T3.B.h0+A.g0.  VMC(4) post-MFMA @ph4/ph8.
// Hazards (stage targets vs last read of that region, all-waves via SBAR):
//  ph1 A.g1/buf1: read ph7-prev, drained pre-MFMA(8) | ph2 B.h1/buf1: read
//  ph6-prev | ph4 A.g0/buf0: aL k1 read ph2, drained pre-MFMA(3); B.h0/buf0:
//  bKb read ph2 (regs carry MFMA(4)) | ph5 A.g1/buf0: aH k1 read ph3, drained
//  pre-MFMA(4) | ph6 B.h1/buf0: read ph2 | ph8 B.h0/A.g0/buf1: read ph5/ph6,
//  drained pre-MFMA(7).  All verified.
#define ITER(T1, T2, T3, FIN)                                                  \
  do {                                                                         \
    short8 aL[4], aH[4], bKa[4], bKb[4];                                       \
    /* ph1 */ SBAR;                                                            \
    stageAg(1, 1, (T1));                                                       \
    LDB4(bKa, 0, k0off); LDA4(aL, 0, 0, k0off); LDA4(aH, 0, 4, k0off);         \
    SCHED0; MF16(aL, bKa, 0);                                                  \
    /* ph2 */ SBAR;                                                            \
    stageB(1, 1, (T1));                                                        \
    LDB4(bKb, 0, k1off); LDA4(aL, 0, 0, k1off);                                \
    SCHED0; MF16(aH, bKa, 4);                                                  \
    /* ph3 */ SBAR;                                                            \
    LDA4(aH, 0, 4, k1off);                                                     \
    SCHED0; MF16(aL, bKb, 0);                                                  \
    /* ph4 */ SBAR;                                                            \
    if (!(FIN)) { stageB(0, 0, (T2)); stageAg(0, 0, (T2)); }                   \
    SCHED0; MF16(aH, bKb, 4);                                                  \
    if (FIN) { VMC(0); } else { VMC(4); }                                      \
    /* ph5 */ SBAR;                                                            \
    if (!(FIN)) stageAg(0, 1, (T2));                                           \
    LDB4(bKa, 1, k0off); LDA4(aL, 1, 0, k0off); LDA4(aH, 1, 4, k0off);         \
    SCHED0; MF16(aL, bKa, 0);                                                  \
    /* ph6 */ SBAR;                                                            \
    if (!(FIN)) stageB(0, 1, (T2));                                            \
    LDB4(bKb, 1, k1off); LDA4(aL, 1, 0, k1off);                                \
    SCHED0; MF16(aH, bKa, 4);                                                  \
    /* ph7 */ SBAR;                                                            \
    LDA4(aH, 1, 4, k1off);                                                     \
    SCHED0; MF16(aL, bKb, 0);                                                  \
    /* ph8 */ SBAR;                                                            \
    if (!(FIN)) { stageB(1, 0, (T3)); stageAg(1, 0, (T3)); }                   \
    SCHED0; MF16(aH, bKb, 4);                                                  \
    if (!(FIN)) { VMC(4); }                                                    \
  } while (0)

__global__ __launch_bounds__(512, 2) void gemm_bt(const uint16_t* __restrict__ A,
                                                  const uint16_t* __restrict__ B,
                                                  float* __restrict__ C) {
  __shared__ __align__(16) uint16_t Ab[2][BM * BK];   // 2 x 32 KiB
  __shared__ __align__(16) uint16_t Bb[2][BN * BK];   // 2 x 32 KiB

  const int tid = threadIdx.x;
  const int wv  = tid >> 6;
  const int l   = tid & 63;

  // XCD-aware mapping, per-XCD concurrent set = 8tm x 4tn (bijective)
  const int xcd = blockIdx.x & 7;
  const int r_  = blockIdx.x >> 3;
  const int tm  = xcd * 8 + ((r_ & 31) >> 2);   // 64 M-tiles
  const int tn  = (r_ >> 5) * 4 + (r_ & 3);     // 16 N-tiles
  const int wm  = wv >> 2;          // 0..1 -> rows wm*128
  const int wn  = wv & 3;           // 0..3 -> cols wn*64

  // ---- staging source (inverse-swizzled global) ----
  const int t8  = tid >> 3;
  const int swz = (tid & 7) ^ ((tid >> 4) & 7);
  const uint16_t* sA = A + (size_t)(tm * BM + t8) * KDIM + swz * 8;
  const uint16_t* sB = B + (size_t)(tn * BN + t8) * KDIM + swz * 8;

  // A read-group staging: g covers rows {g*64 + j*128 + 0..63}, j = 0,1
  auto stageAg = [&](int buf, int g, int tk) {
    #pragma unroll
    for (int j = 0; j < 2; ++j)
      __builtin_amdgcn_global_load_lds(
          (const __attribute__((address_space(1))) unsigned int*)
              (sA + (size_t)(g * 64 + j * 128) * KDIM + tk * BK),
          (__attribute__((address_space(3))) unsigned int*)
              ((char*)&Ab[buf][0] + g * 8192 + j * 16384 + wv * 1024),
          16, 0, 0);
  };
  auto stageB = [&](int buf, int half, int tk) {
    #pragma unroll
    for (int j = 0; j < 2; ++j)
      __builtin_amdgcn_global_load_lds(
          (const __attribute__((address_space(1))) unsigned int*)
              (sB + (size_t)(half * 128 + j * 64) * KDIM + tk * BK),
          (__attribute__((address_space(3))) unsigned int*)
              ((char*)&Bb[buf][0] + half * 16384 + j * 8192 + wv * 1024),
          16, 0, 0);
  };

  // ---- swizzled ds_read bases ----
  const int lA = l & 15, hi = l >> 4;
  const int xr = (lA >> 1) & 7;
  const int k0off = (hi ^ xr) * 16;
  const int k1off = k0off ^ 64;
  const char* aRd = (const char*)&Ab[0][0] + (wm * 128 + lA) * 128;
  const char* bRd = (const char*)&Bb[0][0] + (wn * 64 + lA) * 128;

  f32x4 acc[8][4] = {};

  // ---- prologue: T0 full (8 loads) + T1.B.h0 + T1.A.g0 (4 loads) ----
  stageAg(0, 0, 0); stageAg(0, 1, 0); stageB(0, 0, 0); stageB(0, 1, 0);
  stageB(1, 0, 1);  stageAg(1, 0, 1);
  VMC(4);            // own T0 loads landed; T1's 4 in flight
                     // (ph1's SBAR syncs all waves before first buf0 read)

  #pragma unroll 1
  for (int i = 0; i < NT / 2 - 1; ++i)     // i = 0..30
    ITER(2 * i + 1, 2 * i + 2, 2 * i + 3, 0);
  ITER(NT - 1, 0, 0, 1);                   // final iteration

  // ---- epilogue: C/D layout col = lane&15, row = (lane>>4)*4 + j ----
  float* Cp = C + (size_t)(tm * BM + wm * 128) * NDIM + tn * BN + wn * 64;
  const int co = hi * 4;
  #pragma unroll
  for (int m = 0; m < 8; ++m)
    #pragma unroll
    for (int n = 0; n < 4; ++n)
      #pragma unroll
      for (int j = 0; j < 4; ++j)
        Cp[(size_t)(m * 16 + co + j) * NDIM + n * 16 + lA] = acc[m][n][j];
}

extern "C" void kernel_launch(void* const* d_in, const int* in_sizes, int n_in,
                              void* d_out, int out_size, void* d_ws, size_t ws_size,
                              hipStream_t stream) {
  (void)in_sizes; (void)n_in; (void)out_size; (void)ws_size;
  const float* x = (const float*)d_in[0];   // (4,4096,4096) f32
  const float* w = (const float*)d_in[1];   // (4096,4096) f32
  float* out = (float*)d_out;               // (4,4096,4096) f32

  uint16_t* xb = (uint16_t*)d_ws;                       // 128 MiB
  uint16_t* wh = xb + (size_t)MDIM * KDIM;              // 32 MiB

  cvt_x_kernel<<<2048, 256, 0, stream>>>(x, xb, (int)((MDIM * (size_t)KDIM) / 8));
  fwht_w_kernel<<<(NDIM * KDIM) / 1024, 256, 0, stream>>>(w, wh);
  gemm_bt<<<(MDIM / BM) * (NDIM / BN), 512, 0, stream>>>(xb, wh, out);
}

// Round 9
// 629.743 us; speedup vs baseline: 1.0140x; 1.0140x over previous
//
#include <hip/hip_runtime.h>
#include <hip/hip_bf16.h>
#include <stdint.h>

// HadLinear: out = blockFWHT1024(x)/32 @ W^T  ==  x @ (blockFWHT1024(W rows)/32)^T
// (1) x f32->bf16, (2) Wh = FWHT(W)/32 -> bf16, (3) bf16 MFMA GEMM.
// GEMM R9 = faithful m201 phase ORDER:
//   { ds_reads(p) | stage(plan) | BARRIER | lgkm(0) | 16 MFMA | [VMC] | BARRIER }
// reads issue BEFORE the leading barrier (barrier transit hides LDS latency);
// trailing barrier closes the WAR window for next phase's stage.
// Skeleton from R7: BM=BN=256, BK=64, 8 waves (2Mx4N), 2-buffer LDS, XOR
// chunk swizzle (both-sides), group-staged A, 8tm x 4tn XCD set, VMC(4)
// post-MFMA at ph4/ph8.

typedef __attribute__((ext_vector_type(8))) short    short8;
typedef __attribute__((ext_vector_type(4))) float    f32x4;
typedef __attribute__((ext_vector_type(8))) uint16_t u16x8;

static constexpr int MDIM = 16384;
static constexpr int NDIM = 4096;
static constexpr int KDIM = 4096;
static constexpr int BM = 256, BN = 256, BK = 64;
static constexpr int NT = KDIM / BK;   // 64 K-tiles, 32 iterations

__device__ __forceinline__ uint16_t f2bf(float f) {
  union { float f; uint32_t u; } c; c.f = f;
  uint32_t u = c.u;
  return (uint16_t)((u + 0x7FFFu + ((u >> 16) & 1u)) >> 16);
}

__global__ __launch_bounds__(256) void cvt_x_kernel(const float* __restrict__ x,
                                                    uint16_t* __restrict__ xb, int n8) {
  int stride = gridDim.x * blockDim.x;
  for (int t = blockIdx.x * blockDim.x + threadIdx.x; t < n8; t += stride) {
    const float4* p = reinterpret_cast<const float4*>(x + (size_t)t * 8);
    float4 a = p[0], b = p[1];
    u16x8 o;
    o[0] = f2bf(a.x); o[1] = f2bf(a.y); o[2] = f2bf(a.z); o[3] = f2bf(a.w);
    o[4] = f2bf(b.x); o[5] = f2bf(b.y); o[6] = f2bf(b.z); o[7] = f2bf(b.w);
    *reinterpret_cast<u16x8*>(xb + (size_t)t * 8) = o;
  }
}

__global__ __launch_bounds__(256) void fwht_w_kernel(const float* __restrict__ W,
                                                     uint16_t* __restrict__ Wh) {
  __shared__ float s[1024];
  const int tid = threadIdx.x;
  const size_t base = (size_t)blockIdx.x * 1024;
  reinterpret_cast<float4*>(s)[tid] = reinterpret_cast<const float4*>(W + base)[tid];
  __syncthreads();
  for (int h = 1; h < 1024; h <<= 1) {
    #pragma unroll
    for (int pp = 0; pp < 2; ++pp) {
      int p = tid + pp * 256;
      int q = p & (h - 1);
      int i = ((p - q) << 1) | q;
      float a = s[i], b = s[i + h];
      s[i] = a + b;
      s[i + h] = a - b;
    }
    __syncthreads();
  }
  #pragma unroll
  for (int pp = 0; pp < 4; ++pp) {
    int i = tid + pp * 256;
    Wh[base + i] = f2bf(s[i] * 0.03125f);
  }
}

// ---------------- 8-phase GEMM: C[M,N] = A[M,K] * B[N,K]^T ----------------
// LDS tile: 256 rows x 8 chunks(16B), chunk (r,c') holds global c = c'^((r>>1)&7).

#define FENCE asm volatile("" ::: "memory")
#define SBAR  do { FENCE; __builtin_amdgcn_s_barrier(); \
                   __builtin_amdgcn_sched_barrier(0); } while (0)
#define LGKM0 do { asm volatile("s_waitcnt lgkmcnt(0)" ::: "memory"); \
                   __builtin_amdgcn_sched_barrier(0); } while (0)
#define VMC(n) do { asm volatile("s_waitcnt vmcnt(" #n ")" ::: "memory"); \
                    __builtin_amdgcn_sched_barrier(0); } while (0)

#define LDA4(DST, BUF, MLO, KOFF)                                              \
  do { _Pragma("unroll")                                                       \
    for (int m_ = 0; m_ < 4; ++m_)                                             \
      DST[m_] = *(const short8*)(aRd + (BUF)*32768 + ((MLO)+m_)*2048 + (KOFF)); \
  } while (0)

#define LDB4(DST, BUF, KOFF)                                                   \
  do { _Pragma("unroll")                                                       \
    for (int n_ = 0; n_ < 4; ++n_)                                             \
      DST[n_] = *(const short8*)(bRd + (BUF)*32768 + n_*2048 + (KOFF));        \
  } while (0)

#define MF16(AF, BF, MB)                                                       \
  do { __builtin_amdgcn_s_setprio(1);                                          \
    _Pragma("unroll")                                                          \
    for (int m_ = 0; m_ < 4; ++m_)                                             \
      _Pragma("unroll")                                                        \
      for (int n_ = 0; n_ < 4; ++n_)                                           \
        acc[(MB)+m_][n_] = __builtin_amdgcn_mfma_f32_16x16x32_bf16(            \
            AF[m_], BF[n_], acc[(MB)+m_][n_], 0, 0, 0);                        \
    __builtin_amdgcn_s_setprio(0);                                             \
  } while (0)

// Reads (R4's k-half-major): ph1 bK.k0+aL.k0 (8) | ph2 aH.k0 (4) |
//   ph3 bK.k1+aL.k1 (8) | ph4 aH.k1 (4); mirrored on buf1 for ph5-8.
// Stages (R7 plan): ph1 T1.A.g1 | ph2 T1.B.h1 | ph4 T2.B.h0+A.g0 |
//   ph5 T2.A.g1 | ph6 T2.B.h1 | ph8 T3.B.h0+A.g0.
// vmcnt ledger: enter ph1 with 4 (T1.Bh0+Ag0); ph1 +2, ph2 +2, ph4 +4 = 12;
//   VMC(4) drains T1's 8 exactly; BAR2(4) -> ph5 reads buf1 safe. Same @ph8.
// WAR: every stage targets a region whose last reads were lgkm0-drained
//   before their wave passed the previous trailing barrier (checked per phase).
#define ITER(T1, T2, T3, FIN)                                                  \
  do {                                                                         \
    short8 aL[4], aH[4], bK[4];                                                \
    /* ph1 */                                                                  \
    LDB4(bK, 0, k0off); LDA4(aL, 0, 0, k0off);                                 \
    stageAg(1, 1, (T1));                                                       \
    SBAR; LGKM0; MF16(aL, bK, 0); SBAR;                                        \
    /* ph2 */                                                                  \
    LDA4(aH, 0, 4, k0off);                                                     \
    stageB(1, 1, (T1));                                                        \
    SBAR; LGKM0; MF16(aH, bK, 4); SBAR;                                        \
    /* ph3 */                                                                  \
    LDB4(bK, 0, k1off); LDA4(aL, 0, 0, k1off);                                 \
    SBAR; LGKM0; MF16(aL, bK, 0); SBAR;                                        \
    /* ph4 */                                                                  \
    LDA4(aH, 0, 4, k1off);                                                     \
    if (!(FIN)) { stageB(0, 0, (T2)); stageAg(0, 0, (T2)); }                   \
    SBAR; LGKM0; MF16(aH, bK, 4);                                              \
    if (FIN) { VMC(0); } else { VMC(4); }                                      \
    SBAR;                                                                      \
    /* ph5 */                                                                  \
    LDB4(bK, 1, k0off); LDA4(aL, 1, 0, k0off);                                 \
    if (!(FIN)) stageAg(0, 1, (T2));                                           \
    SBAR; LGKM0; MF16(aL, bK, 0); SBAR;                                        \
    /* ph6 */                                                                  \
    LDA4(aH, 1, 4, k0off);                                                     \
    if (!(FIN)) stageB(0, 1, (T2));                                            \
    SBAR; LGKM0; MF16(aH, bK, 4); SBAR;                                        \
    /* ph7 */                                                                  \
    LDB4(bK, 1, k1off); LDA4(aL, 1, 0, k1off);                                 \
    SBAR; LGKM0; MF16(aL, bK, 0); SBAR;                                        \
    /* ph8 */                                                                  \
    LDA4(aH, 1, 4, k1off);                                                     \
    if (!(FIN)) { stageB(1, 0, (T3)); stageAg(1, 0, (T3)); }                   \
    SBAR; LGKM0; MF16(aH, bK, 4);                                              \
    if (!(FIN)) { VMC(4); SBAR; }                                              \
  } while (0)

__global__ __launch_bounds__(512, 2) void gemm_bt(const uint16_t* __restrict__ A,
                                                  const uint16_t* __restrict__ B,
                                                  float* __restrict__ C) {
  __shared__ __align__(16) uint16_t Ab[2][BM * BK];   // 2 x 32 KiB
  __shared__ __align__(16) uint16_t Bb[2][BN * BK];   // 2 x 32 KiB

  const int tid = threadIdx.x;
  const int wv  = tid >> 6;
  const int l   = tid & 63;

  // XCD-aware mapping, per-XCD concurrent set = 8tm x 4tn (bijective)
  const int xcd = blockIdx.x & 7;
  const int r_  = blockIdx.x >> 3;
  const int tm  = xcd * 8 + ((r_ & 31) >> 2);   // 64 M-tiles
  const int tn  = (r_ >> 5) * 4 + (r_ & 3);     // 16 N-tiles
  const int wm  = wv >> 2;          // 0..1 -> rows wm*128
  const int wn  = wv & 3;           // 0..3 -> cols wn*64

  // ---- staging source (inverse-swizzled global) ----
  const int t8  = tid >> 3;
  const int swz = (tid & 7) ^ ((tid >> 4) & 7);
  const uint16_t* sA = A + (size_t)(tm * BM + t8) * KDIM + swz * 8;
  const uint16_t* sB = B + (size_t)(tn * BN + t8) * KDIM + swz * 8;

  // A read-group staging: g covers rows {g*64 + j*128 + 0..63}, j = 0,1
  auto stageAg = [&](int buf, int g, int tk) {
    #pragma unroll
    for (int j = 0; j < 2; ++j)
      __builtin_amdgcn_global_load_lds(
          (const __attribute__((address_space(1))) unsigned int*)
              (sA + (size_t)(g * 64 + j * 128) * KDIM + tk * BK),
          (__attribute__((address_space(3))) unsigned int*)
              ((char*)&Ab[buf][0] + g * 8192 + j * 16384 + wv * 1024),
          16, 0, 0);
  };
  auto stageB = [&](int buf, int half, int tk) {
    #pragma unroll
    for (int j = 0; j < 2; ++j)
      __builtin_amdgcn_global_load_lds(
          (const __attribute__((address_space(1))) unsigned int*)
              (sB + (size_t)(half * 128 + j * 64) * KDIM + tk * BK),
          (__attribute__((address_space(3))) unsigned int*)
              ((char*)&Bb[buf][0] + half * 16384 + j * 8192 + wv * 1024),
          16, 0, 0);
  };

  // ---- swizzled ds_read bases ----
  const int lA = l & 15, hi = l >> 4;
  const int xr = (lA >> 1) & 7;
  const int k0off = (hi ^ xr) * 16;
  const int k1off = k0off ^ 64;
  const char* aRd = (const char*)&Ab[0][0] + (wm * 128 + lA) * 128;
  const char* bRd = (const char*)&Bb[0][0] + (wn * 64 + lA) * 128;

  f32x4 acc[8][4] = {};

  // ---- prologue: T0 full (8 loads) + T1.B.h0 + T1.A.g0 (4 loads) ----
  stageAg(0, 0, 0); stageAg(0, 1, 0); stageB(0, 0, 0); stageB(0, 1, 0);
  stageB(1, 0, 1);  stageAg(1, 0, 1);
  VMC(4);            // own T0 loads landed; T1's 4 in flight
  SBAR;              // all waves' T0 landed -> buf0 readable (ph1 reads pre-BAR)

  #pragma unroll 1
  for (int i = 0; i < NT / 2 - 1; ++i)     // i = 0..30
    ITER(2 * i + 1, 2 * i + 2, 2 * i + 3, 0);
  ITER(NT - 1, 0, 0, 1);                   // final iteration

  // ---- epilogue: C/D layout col = lane&15, row = (lane>>4)*4 + j ----
  float* Cp = C + (size_t)(tm * BM + wm * 128) * NDIM + tn * BN + wn * 64;
  const int co = hi * 4;
  #pragma unroll
  for (int m = 0; m < 8; ++m)
    #pragma unroll
    for (int n = 0; n < 4; ++n)
      #pragma unroll
      for (int j = 0; j < 4; ++j)
        Cp[(size_t)(m * 16 + co + j) * NDIM + n * 16 + lA] = acc[m][n][j];
}

extern "C" void kernel_launch(void* const* d_in, const int* in_sizes, int n_in,
                              void* d_out, int out_size, void* d_ws, size_t ws_size,
                              hipStream_t stream) {
  (void)in_sizes; (void)n_in; (void)out_size; (void)ws_size;
  const float* x = (const float*)d_in[0];   // (4,4096,4096) f32
  const float* w = (const float*)d_in[1];   // (4096,4096) f32
  float* out = (float*)d_out;               // (4,4096,4096) f32

  uint16_t* xb = (uint16_t*)d_ws;                       // 128 MiB
  uint16_t* wh = xb + (size_t)MDIM * KDIM;              // 32 MiB

  cvt_x_kernel<<<2048, 256, 0, stream>>>(x, xb, (int)((MDIM * (size_t)KDIM) / 8));
  fwht_w_kernel<<<(NDIM * KDIM) / 1024, 256, 0, stream>>>(w, wh);
  gemm_bt<<<(MDIM / BM) * (NDIM / BN), 512, 0, stream>>>(xb, wh, out);
}